// Round 1
// baseline (3003.842 us; speedup 1.0000x reference)
//
#include <hip/hip_runtime.h>

// Problem: B=32, T=24, SIZE=768.
//   v_0 = param + 1
//   y_t[b,k] = sum_i v_t[b,i] * inp[b,t,i,k];  v_{t+1} = relu(y_t)
//   output = y_{T-1} (pre-ReLU), shape [B, SIZE], fp32.
// Memory-bound: input 1.81 GB read once -> ~288 us floor at 6.3 TB/s.

#define NB   32
#define NT   24
#define NSZ  768
#define GPB  12            // blocks per batch (column groups)
#define NCOLS 64           // columns per block
#define NTHREADS 256
#define NSLICES 16         // i-dimension split within a block
#define ROWS 48            // NSZ / NSLICES

#define CNT_STRIDE 16      // ints (64B) per counter to avoid false sharing
#define CNT_INTS (NB * NT * CNT_STRIDE)

__global__ __launch_bounds__(NTHREADS, 4)
void chain_matvec_kernel(const float* __restrict__ inp,
                         const float* __restrict__ param,
                         float* __restrict__ out,
                         int* __restrict__ cnt,
                         float* __restrict__ vbuf)
{
    __shared__ float v[NSZ];
    __shared__ float red[NSLICES][NCOLS + 4];   // +4 floats keeps 16B row alignment

    const int tid = threadIdx.x;
    const int b  = blockIdx.x & (NB - 1);       // batch: consecutive blocks -> different batches
    const int g  = blockIdx.x >> 5;             // column group 0..11
    const int c0 = g * NCOLS;

    const int col4  = tid & 15;                 // which float4 of the 64-col chunk
    const int slice = tid >> 4;                 // 0..15
    const int i0    = slice * ROWS;

    // v_0 = param + 1
    for (int j = tid; j < NSZ; j += NTHREADS) v[j] = param[j] + 1.0f;
    __syncthreads();

    for (int t = 0; t < NT; ++t) {
        const float* mat = inp + (size_t)(b * NT + t) * (size_t)(NSZ * NSZ);
        const float4* p  = (const float4*)(mat + (size_t)i0 * NSZ + c0) + col4;

        float4 acc = {0.f, 0.f, 0.f, 0.f};
        #pragma unroll 8
        for (int j = 0; j < ROWS; ++j) {
            const float  s = v[i0 + j];
            const float4 m = p[j * (NSZ / 4)];
            acc.x = fmaf(s, m.x, acc.x);
            acc.y = fmaf(s, m.y, acc.y);
            acc.z = fmaf(s, m.z, acc.z);
            acc.w = fmaf(s, m.w, acc.w);
        }
        ((float4*)&red[slice][0])[col4] = acc;
        __syncthreads();

        if (t == NT - 1) {
            // last step: output is PRE-ReLU y
            if (tid < NCOLS) {
                float y = 0.f;
                #pragma unroll
                for (int s = 0; s < NSLICES; ++s) y += red[s][tid];
                out[b * NSZ + c0 + tid] = y;
            }
            return;   // uniform exit, no further sync needed
        }

        // publish relu(y) chunk to double-buffered global v
        if (tid < NCOLS) {
            float y = 0.f;
            #pragma unroll
            for (int s = 0; s < NSLICES; ++s) y += red[s][tid];
            const float r = fmaxf(y, 0.f);
            __hip_atomic_store(&vbuf[((t + 1) & 1) * (NB * NSZ) + b * NSZ + c0 + tid],
                               r, __ATOMIC_RELAXED, __HIP_MEMORY_SCOPE_AGENT);
        }
        __syncthreads();   // all chunk stores issued (vmcnt drained before barrier)

        // per-batch sync: 12 blocks rendezvous on a padded counter
        if (tid == 0) {
            int* c = &cnt[(b * NT + t) * CNT_STRIDE];
            __hip_atomic_fetch_add(c, 1, __ATOMIC_RELEASE, __HIP_MEMORY_SCOPE_AGENT);
            while (__hip_atomic_load(c, __ATOMIC_ACQUIRE, __HIP_MEMORY_SCOPE_AGENT) < GPB)
                __builtin_amdgcn_s_sleep(4);
        }
        __syncthreads();

        // reload the full next-step v (agent-scope loads: cross-XCD coherent)
        float* vsrc = &vbuf[((t + 1) & 1) * (NB * NSZ) + b * NSZ];
        for (int j = tid; j < NSZ; j += NTHREADS)
            v[j] = __hip_atomic_load(&vsrc[j], __ATOMIC_RELAXED, __HIP_MEMORY_SCOPE_AGENT);
        __syncthreads();
    }
}

extern "C" void kernel_launch(void* const* d_in, const int* in_sizes, int n_in,
                              void* d_out, int out_size, void* d_ws, size_t ws_size,
                              hipStream_t stream)
{
    const float* inp   = (const float*)d_in[0];   // [B, T, SIZE, SIZE] fp32
    const float* param = (const float*)d_in[1];   // [SIZE] fp32
    float* out = (float*)d_out;                   // [B, SIZE] fp32

    // workspace layout: [counters: CNT_INTS ints][vbuf: 2*B*SIZE floats]
    int*   cnt  = (int*)d_ws;
    float* vbuf = (float*)d_ws + CNT_INTS;

    // counters must start at 0 every call (ws is poisoned to 0xAA)
    hipMemsetAsync(d_ws, 0, CNT_INTS * sizeof(int), stream);

    void* args[] = {(void*)&inp, (void*)&param, (void*)&out, (void*)&cnt, (void*)&vbuf};
    hipLaunchCooperativeKernel(reinterpret_cast<void*>(chain_matvec_kernel),
                               dim3(NB * GPB), dim3(NTHREADS), args, 0, stream);
}